// Round 12
// baseline (16274.571 us; speedup 1.0000x reference)
//
#include <hip/hip_runtime.h>
#include <stdint.h>

#define NCU 256
#define TPB 512
#define IN_DIM 1024
#define HID1   1024
#define HID2   2048
#define T_STEPS 2048

// LL exchange (r10, proven): {payload,tag} 8-B pairs inside ONE 64-B sector.
// 8-B store = single transaction -> tag visible <=> payload visible.
// lines1: 4 pairs (h1). lines2: 8 pairs (h2). 64-B stride, 4 buffers deep.
#define LINE_DW 16

typedef float    f32x4 __attribute__((ext_vector_type(4)));
typedef uint32_t u32x4 __attribute__((ext_vector_type(4)));
typedef uint32_t u32x2 __attribute__((ext_vector_type(2)));
typedef __fp16   h16x2 __attribute__((ext_vector_type(2)));

__device__ __forceinline__ uint32_t pkh(float a, float b){
  h16x2 h = __builtin_amdgcn_cvt_pkrtz(a, b);
  uint32_t u; __builtin_memcpy(&u, &h, 4); return u;
}
__device__ __forceinline__ uint32_t pkhu(uint32_t a, uint32_t b){
  return pkh(__uint_as_float(a), __uint_as_float(b));
}

#if __has_builtin(__builtin_amdgcn_fdot2)
__device__ __forceinline__ float fdot2_(uint32_t w, uint32_t h, float c){
  h16x2 wf, hf; __builtin_memcpy(&wf, &w, 4); __builtin_memcpy(&hf, &h, 4);
  return __builtin_amdgcn_fdot2(wf, hf, c, false);
}
#else
__device__ __forceinline__ float fdot2_(uint32_t w, uint32_t h, float c){
  h16x2 wf, hf; __builtin_memcpy(&wf, &w, 4); __builtin_memcpy(&hf, &h, 4);
  c = fmaf((float)wf[0], (float)hf[0], c);
  return fmaf((float)wf[1], (float)hf[1], c);
}
#endif

__device__ __forceinline__ float dot16(u32x4 w, u32x4 h, float c){
  c = fdot2_(w[0], h[0], c); c = fdot2_(w[1], h[1], c);
  c = fdot2_(w[2], h[2], c); c = fdot2_(w[3], h[3], c);
  return c;
}

__device__ __forceinline__ float wave_reduce(float v){
  v += __shfl_xor(v, 32); v += __shfl_xor(v, 16); v += __shfl_xor(v, 8);
  v += __shfl_xor(v, 4);  v += __shfl_xor(v, 2);  v += __shfl_xor(v, 1);
  return v;
}

__device__ __forceinline__ float sigm_(float x){
  return __builtin_amdgcn_rcpf(1.f + __expf(-x));
}
__device__ __forceinline__ float tanh_(float x){
  float e = __expf(2.f * x);
  return (e - 1.f) * __builtin_amdgcn_rcpf(e + 1.f);
}

__global__ void prep_kernel(uint32_t* __restrict__ lines)
{
  int idx = blockIdx.x * blockDim.x + threadIdx.x;
  const int total = 2 * 4 * NCU * LINE_DW;
  for (int i = idx; i < total; i += gridDim.x * blockDim.x)
    __hip_atomic_store(lines + i, 0u, __ATOMIC_RELAXED, __HIP_MEMORY_SCOPE_AGENT);
}

// ---------------------------------------------------------------------------
// persistent 2-layer LSTM. 256 blocks x 512 threads (8 waves).
// Block b owns layer1 units [4b,4b+4), layer2 units [8b,8b+8).
// OWNER-COMPUTES: each compute wave owns 2 units end-to-end (all 4 gate rows,
// reduce, gates, c-state in lanes 0-1, immediate publish). No gsum handoff.
//  waves 0-1: layer1 units {2wv,2wv+1}: phaseA -> publish h1[t] -> gather h1[t]
//  waves 2-5: layer2 units {2(wv-2),2(wv-2)+1}: phaseB -> publish h2[t-2]
//  waves 6-7: poll+gather h2[t-2] (overlaps phase B + flight)
// ONE barrier per iteration. h1 triple-buffered, h2 double-buffered:
//  phaseA reads h1[(t+2)%3], phaseB reads h1[(t+1)%3] & h2[(t+1)&1];
//  gathers write h1[t%3], h2[t&1] - never a buffer being read this iter.
// ---------------------------------------------------------------------------
__global__ __launch_bounds__(TPB, 1) void lstm_persist(
    const float* __restrict__ x,    const float* __restrict__ Wih1,
    const float* __restrict__ Whh1, const float* __restrict__ b1,
    const float* __restrict__ Wih2, const float* __restrict__ Whh2,
    const float* __restrict__ b2,   const float* __restrict__ Wout,
    uint32_t* __restrict__ lines,   float* __restrict__ partial_out)
{
  __shared__ u32x4 whh2_u4[32 * 256];   // 128 KiB f16 Whh2 (granules)
  __shared__ u32x4 h1g[3][128];         // h1 f16, triple-buffered (3 x 2 KiB)
  __shared__ u32x4 h2g[2][256];         // h2 f16, double-buffered (2 x 4 KiB)
  __shared__ float gx1v[16];

  uint32_t* lines1 = lines;
  uint32_t* lines2 = lines + 4 * NCU * LINE_DW;

  const int b    = blockIdx.x;
  const int tid  = threadIdx.x;
  const int lane = tid & 63;
  const int wv   = tid >> 6;

  // ---- init: Whh2 slice -> LDS f16 granules (all waves) ----
  for (int i = tid; i < 32 * 256; i += TPB) {
    int lr = i >> 8, u = i & 255;
    int g = lr >> 3, uu2 = lr & 7;
    const f32x4* s4 = (const f32x4*)(Whh2 + (int64_t)(g * HID2 + 8 * b + uu2) * HID2);
    f32x4 lo = s4[2 * u], hi = s4[2 * u + 1];
    u32x4 wv4;
    wv4[0] = pkh(lo[0], lo[1]); wv4[1] = pkh(lo[2], lo[3]);
    wv4[2] = pkh(hi[0], hi[1]); wv4[3] = pkh(hi[2], hi[3]);
    whh2_u4[i] = wv4;
  }

  // ---- gx1 = Wih1 @ x + b1 (constant over t; 2 rows/wave) ----
  #pragma unroll
  for (int rr = 0; rr < 2; ++rr) {
    int lr1 = wv * 2 + rr;                 // = gate*4 + unit
    int g = lr1 >> 2, uu = lr1 & 3;
    int row = g * HID1 + 4 * b + uu;
    float s = 0.f;
    #pragma unroll
    for (int j = 0; j < 16; ++j)
      s += Wih1[(int64_t)row * IN_DIM + lane + 64 * j] * x[lane + 64 * j];
    s = wave_reduce(s);
    if (lane == 0) gx1v[lr1] = s + b1[row];
  }
  {
    u32x4 z; z[0] = z[1] = z[2] = z[3] = 0u;
    for (int i = tid; i < 3 * 128; i += TPB) ((u32x4*)h1g)[i] = z;
    for (int i = tid; i < 2 * 256; i += TPB) ((u32x4*)h2g)[i] = z;
  }
  __syncthreads();   // gx1v ready

  // ---- role-dependent register weights (ONE shared array, role content) ----
  // waves 0-1: wreg[2g+j] = Whh1 row (gate g, unit 2wv+j), full-width.
  // waves 2-5: wreg[2g+j] = Wih2 row (gate g, unit U+j), U=2(wv-2).
  u32x4 wreg[8][2];
  float biasr[4];          // waves0-1: gx1 for my unit; waves2-5: b2
  float woutr = 0.f;
  const int U  = 2 * (wv - 2);
  const int jl = lane & 1;
  if (wv < 2) {
    #pragma unroll
    for (int idx = 0; idx < 8; ++idx) {
      int g = idx >> 1, j = idx & 1;
      int uu = 2 * wv + j;
      const f32x4* s4 = (const f32x4*)(Whh1 + (int64_t)(g * HID1 + 4 * b + uu) * IN_DIM);
      #pragma unroll
      for (int q = 0; q < 2; ++q) {
        int u = lane + 64 * q;
        f32x4 lo = s4[2 * u], hi = s4[2 * u + 1];
        u32x4 w4;
        w4[0] = pkh(lo[0], lo[1]); w4[1] = pkh(lo[2], lo[3]);
        w4[2] = pkh(hi[0], hi[1]); w4[3] = pkh(hi[2], hi[3]);
        wreg[idx][q] = w4;
      }
    }
    int uu = 2 * wv + jl;
    #pragma unroll
    for (int g = 0; g < 4; ++g) biasr[g] = gx1v[g * 4 + uu];
  } else if (wv < 6) {
    #pragma unroll
    for (int idx = 0; idx < 8; ++idx) {
      int g = idx >> 1, j = idx & 1;
      int uu = U + j;
      const f32x4* s4 = (const f32x4*)(Wih2 + (int64_t)(g * HID2 + 8 * b + uu) * IN_DIM);
      #pragma unroll
      for (int q = 0; q < 2; ++q) {
        int u = lane + 64 * q;
        f32x4 lo = s4[2 * u], hi = s4[2 * u + 1];
        u32x4 w4;
        w4[0] = pkh(lo[0], lo[1]); w4[1] = pkh(lo[2], lo[3]);
        w4[2] = pkh(hi[0], hi[1]); w4[3] = pkh(hi[2], hi[3]);
        wreg[idx][q] = w4;
      }
    }
    int uu = U + jl;
    #pragma unroll
    for (int g = 0; g < 4; ++g) biasr[g] = b2[g * HID2 + 8 * b + uu];
    woutr = Wout[8 * b + uu];
  }

  float creg = 0.f;        // c1 (waves0-1 lanes0-1) or c2 (waves2-5 lanes0-1)
  __syncthreads();

  // ---- time loop: ONE barrier per iteration ----
  for (int t = 0; t < T_STEPS + 2; ++t) {
    const int bufP = t & 3;
    const uint32_t tg = (uint32_t)(t + 1);

    if (wv < 2) {
      // ======== layer 1 owner: phaseA -> gates -> publish -> gather ========
      if (t < T_STEPS) {
        const u32x4* h1A = h1g[(t + 2) % 3];        // h1[t-1]
        u32x4 ha0 = h1A[lane], ha1 = h1A[64 + lane];
        float acc[8];
        #pragma unroll
        for (int idx = 0; idx < 8; ++idx) {
          float s = dot16(wreg[idx][0], ha0, 0.f);
          acc[idx] = dot16(wreg[idx][1], ha1, s);
        }
        #pragma unroll
        for (int idx = 0; idx < 8; ++idx) acc[idx] = wave_reduce(acc[idx]);
        if (lane < 2) {
          float gi = sigm_(acc[0 + jl] + biasr[0]);
          float gf = sigm_(acc[2 + jl] + biasr[1]);
          float gg = tanh_(acc[4 + jl] + biasr[2]);
          float go = sigm_(acc[6 + jl] + biasr[3]);
          creg = gf * creg + gi * gg;
          float h1v = go * tanh_(creg);
          int p = 2 * wv + jl;
          uint32_t* ptr = lines1 + ((size_t)bufP * NCU + b) * LINE_DW + 2 * p;
          u32x2 st; st[0] = __float_as_uint(h1v); st[1] = tg;
          asm volatile("global_store_dwordx2 %0, %1, off sc0 sc1"
                       :: "v"(ptr), "v"(st) : "memory");
        }
        // gather h1[t]: 128 threads (waves0-1), 2 sources each
        const int g0 = tid;                          // 0..127
        const uint32_t* lA = lines1 + ((size_t)bufP * NCU + g0) * LINE_DW;
        const uint32_t* lB = lines1 + ((size_t)bufP * NCU + 128 + g0) * LINE_DW;
        bool dA = false, dB = false;
        while (!dA || !dB) {
          u32x4 a0, a1, c0, c1;
          if (!dA) {
            asm volatile("global_load_dwordx4 %0, %1, off sc0 sc1"
                         : "=&v"(a0) : "v"(lA));
            asm volatile("global_load_dwordx4 %0, %1, off offset:16 sc0 sc1"
                         : "=&v"(a1) : "v"(lA));
          }
          if (!dB) {
            asm volatile("global_load_dwordx4 %0, %1, off sc0 sc1"
                         : "=&v"(c0) : "v"(lB));
            asm volatile("global_load_dwordx4 %0, %1, off offset:16 sc0 sc1"
                         : "=&v"(c1) : "v"(lB));
          }
          asm volatile("s_waitcnt vmcnt(0)" ::: "memory");
          if (!dA && a0[1] == tg && a0[3] == tg && a1[1] == tg && a1[3] == tg) {
            u32x2 hp; hp[0] = pkhu(a0[0], a0[2]); hp[1] = pkhu(a1[0], a1[2]);
            ((u32x2*)h1g[t % 3])[g0] = hp;
            dA = true;
          }
          if (!dB && c0[1] == tg && c0[3] == tg && c1[1] == tg && c1[3] == tg) {
            u32x2 hp; hp[0] = pkhu(c0[0], c0[2]); hp[1] = pkhu(c1[0], c1[2]);
            ((u32x2*)h1g[t % 3])[128 + g0] = hp;
            dB = true;
          }
          if (!dA || !dB) __builtin_amdgcn_s_sleep(1);
        }
      }
    } else if (wv < 6) {
      // ======== layer 2 owner: phaseB -> gates -> publish -> partial ========
      if (t >= 2) {
        const u32x4* h1B = h1g[(t + 1) % 3];        // h1[t-2]
        u32x4 x1a = h1B[lane], x1b = h1B[64 + lane];
        const u32x4* h2B = h2g[(t + 1) & 1];        // h2[t-3]
        u32x4 x20 = h2B[lane],       x21 = h2B[64 + lane];
        u32x4 x22 = h2B[128 + lane], x23 = h2B[192 + lane];
        float acc[8];
        #pragma unroll
        for (int idx = 0; idx < 8; ++idx) {
          int g = idx >> 1, j = idx & 1;
          int lr = 8 * g + U + j;
          const u32x4* wrow = &whh2_u4[lr * 256];
          float s = dot16(wreg[idx][0], x1a, 0.f);
          s = dot16(wreg[idx][1], x1b, s);
          s = dot16(wrow[lane],       x20, s);
          s = dot16(wrow[64 + lane],  x21, s);
          s = dot16(wrow[128 + lane], x22, s);
          acc[idx] = dot16(wrow[192 + lane], x23, s);
        }
        #pragma unroll
        for (int idx = 0; idx < 8; ++idx) acc[idx] = wave_reduce(acc[idx]);
        if (lane < 2) {
          float gi = sigm_(acc[0 + jl] + biasr[0]);
          float gf = sigm_(acc[2 + jl] + biasr[1]);
          float gg = tanh_(acc[4 + jl] + biasr[2]);
          float go = sigm_(acc[6 + jl] + biasr[3]);
          creg = gf * creg + gi * gg;
          float h2v = go * tanh_(creg);
          int p = U + jl;
          if (t <= T_STEPS) {
            uint32_t* ptr = lines2 + ((size_t)bufP * NCU + b) * LINE_DW + 2 * p;
            u32x2 st; st[0] = __float_as_uint(h2v); st[1] = tg;
            asm volatile("global_store_dwordx2 %0, %1, off sc0 sc1"
                         :: "v"(ptr), "v"(st) : "memory");
          }
          partial_out[((int64_t)(t - 2) * NCU + b) * 8 + p] = h2v * woutr;
        }
      }
    } else {
      // ======== h2 gatherers: 128 threads (waves6-7), 2 sources each ========
      if (t >= 2 && t <= T_STEPS) {
        const int g0 = tid - 384;                    // 0..127
        const uint32_t* lA = lines2 + ((size_t)bufP * NCU + g0) * LINE_DW;
        const uint32_t* lB = lines2 + ((size_t)bufP * NCU + 128 + g0) * LINE_DW;
        bool dA = false, dB = false;
        while (!dA || !dB) {
          u32x4 d0, d1, d2, d3, e0, e1, e2, e3;
          if (!dA) {
            asm volatile("global_load_dwordx4 %0, %1, off sc0 sc1"
                         : "=&v"(d0) : "v"(lA));
            asm volatile("global_load_dwordx4 %0, %1, off offset:16 sc0 sc1"
                         : "=&v"(d1) : "v"(lA));
            asm volatile("global_load_dwordx4 %0, %1, off offset:32 sc0 sc1"
                         : "=&v"(d2) : "v"(lA));
            asm volatile("global_load_dwordx4 %0, %1, off offset:48 sc0 sc1"
                         : "=&v"(d3) : "v"(lA));
          }
          if (!dB) {
            asm volatile("global_load_dwordx4 %0, %1, off sc0 sc1"
                         : "=&v"(e0) : "v"(lB));
            asm volatile("global_load_dwordx4 %0, %1, off offset:16 sc0 sc1"
                         : "=&v"(e1) : "v"(lB));
            asm volatile("global_load_dwordx4 %0, %1, off offset:32 sc0 sc1"
                         : "=&v"(e2) : "v"(lB));
            asm volatile("global_load_dwordx4 %0, %1, off offset:48 sc0 sc1"
                         : "=&v"(e3) : "v"(lB));
          }
          asm volatile("s_waitcnt vmcnt(0)" ::: "memory");
          if (!dA && d0[1] == tg && d0[3] == tg && d1[1] == tg && d1[3] == tg &&
              d2[1] == tg && d2[3] == tg && d3[1] == tg && d3[3] == tg) {
            u32x4 hp;
            hp[0] = pkhu(d0[0], d0[2]); hp[1] = pkhu(d1[0], d1[2]);
            hp[2] = pkhu(d2[0], d2[2]); hp[3] = pkhu(d3[0], d3[2]);
            h2g[t & 1][g0] = hp;
            dA = true;
          }
          if (!dB && e0[1] == tg && e0[3] == tg && e1[1] == tg && e1[3] == tg &&
              e2[1] == tg && e2[3] == tg && e3[1] == tg && e3[3] == tg) {
            u32x4 hp;
            hp[0] = pkhu(e0[0], e0[2]); hp[1] = pkhu(e1[0], e1[2]);
            hp[2] = pkhu(e2[0], e2[2]); hp[3] = pkhu(e3[0], e3[2]);
            h2g[t & 1][128 + g0] = hp;
            dB = true;
          }
          if (!dA || !dB) __builtin_amdgcn_s_sleep(1);
        }
      }
    }
    __syncthreads();   // single barrier: gathered LDS visible next iteration
  }
}

// ---------------------------------------------------------------------------
// out[t] = sum over 2048 per-unit partials + bout
// ---------------------------------------------------------------------------
__global__ void out_reduce(const float* __restrict__ partial_out,
                           const float* __restrict__ bout,
                           float* __restrict__ out)
{
  int t = blockIdx.x;
  int lane = threadIdx.x;   // 64 threads
  float s = 0.f;
  #pragma unroll
  for (int q = 0; q < 32; ++q) s += partial_out[(int64_t)t * (NCU * 8) + lane + 64 * q];
  s = wave_reduce(s);
  if (lane == 0) out[t] = s + bout[0];
}

extern "C" void kernel_launch(void* const* d_in, const int* in_sizes, int n_in,
                              void* d_out, int out_size, void* d_ws, size_t ws_size,
                              hipStream_t stream)
{
  const float* x    = (const float*)d_in[0];
  const float* Wih1 = (const float*)d_in[1];
  const float* Whh1 = (const float*)d_in[2];
  const float* b1   = (const float*)d_in[3];
  const float* Wih2 = (const float*)d_in[4];
  const float* Whh2 = (const float*)d_in[5];
  const float* b2   = (const float*)d_in[6];
  const float* Wout = (const float*)d_in[7];
  const float* bout = (const float*)d_in[8];
  float* out = (float*)d_out;

  char* ws = (char*)d_ws;
  size_t off = 0;
  auto take = [&](size_t bytes) -> char* {
    char* p = ws + off;
    off = (off + bytes + 255) & ~(size_t)255;
    return p;
  };
  uint32_t* lines    = (uint32_t*)take((size_t)2 * 4 * NCU * LINE_DW * 4);   // 128 KB
  float* partial_out = (float*)take((size_t)T_STEPS * NCU * 8 * 4);          // 16.8 MB

  if (off > ws_size) return;

  hipLaunchKernelGGL(prep_kernel, dim3(32), dim3(256), 0, stream, lines);

  void* args[] = { &x, &Wih1, &Whh1, &b1, &Wih2, &Whh2, &b2, &Wout,
                   &lines, &partial_out };
  (void)hipLaunchCooperativeKernel((void*)lstm_persist, dim3(NCU), dim3(TPB),
                                   args, 0, stream);

  hipLaunchKernelGGL(out_reduce, dim3(T_STEPS), dim3(64), 0, stream,
                     partial_out, bout, out);
}

// Round 13
// 6655.766 us; speedup vs baseline: 2.4452x; 2.4452x over previous
//
#include <hip/hip_runtime.h>
#include <stdint.h>

#define NCU 256
#define TPB 512
#define IN_DIM 1024
#define HID1   1024
#define HID2   2048
#define T_STEPS 2048

// LL exchange (r10, proven): {payload,tag} 8-B pairs inside ONE 64-B sector.
// 8-B store = single transaction -> tag visible <=> payload visible.
// lines1: 4 pairs (h1). lines2: 8 pairs (h2). 64-B stride, 4 buffers deep.
#define LINE_DW 16

typedef float    f32x4 __attribute__((ext_vector_type(4)));
typedef uint32_t u32x4 __attribute__((ext_vector_type(4)));
typedef uint32_t u32x2 __attribute__((ext_vector_type(2)));
typedef __fp16   h16x2 __attribute__((ext_vector_type(2)));

__device__ __forceinline__ uint32_t pkh(float a, float b){
  h16x2 h = __builtin_amdgcn_cvt_pkrtz(a, b);
  uint32_t u; __builtin_memcpy(&u, &h, 4); return u;
}
__device__ __forceinline__ uint32_t pkhu(uint32_t a, uint32_t b){
  return pkh(__uint_as_float(a), __uint_as_float(b));
}

#if __has_builtin(__builtin_amdgcn_fdot2)
__device__ __forceinline__ float fdot2_(uint32_t w, uint32_t h, float c){
  h16x2 wf, hf; __builtin_memcpy(&wf, &w, 4); __builtin_memcpy(&hf, &h, 4);
  return __builtin_amdgcn_fdot2(wf, hf, c, false);
}
#else
__device__ __forceinline__ float fdot2_(uint32_t w, uint32_t h, float c){
  h16x2 wf, hf; __builtin_memcpy(&wf, &w, 4); __builtin_memcpy(&hf, &h, 4);
  c = fmaf((float)wf[0], (float)hf[0], c);
  return fmaf((float)wf[1], (float)hf[1], c);
}
#endif

__device__ __forceinline__ float dot16(u32x4 w, u32x4 h, float c){
  c = fdot2_(w[0], h[0], c); c = fdot2_(w[1], h[1], c);
  c = fdot2_(w[2], h[2], c); c = fdot2_(w[3], h[3], c);
  return c;
}

__device__ __forceinline__ float wave_reduce(float v){
  v += __shfl_xor(v, 32); v += __shfl_xor(v, 16); v += __shfl_xor(v, 8);
  v += __shfl_xor(v, 4);  v += __shfl_xor(v, 2);  v += __shfl_xor(v, 1);
  return v;
}

__device__ __forceinline__ float sigm_(float x){
  return __builtin_amdgcn_rcpf(1.f + __expf(-x));
}
__device__ __forceinline__ float tanh_(float x){
  float e = __expf(2.f * x);
  return (e - 1.f) * __builtin_amdgcn_rcpf(e + 1.f);
}

__global__ void prep_kernel(uint32_t* __restrict__ lines)
{
  int idx = blockIdx.x * blockDim.x + threadIdx.x;
  const int total = 2 * 4 * NCU * LINE_DW;
  for (int i = idx; i < total; i += gridDim.x * blockDim.x)
    __hip_atomic_store(lines + i, 0u, __ATOMIC_RELAXED, __HIP_MEMORY_SCOPE_AGENT);
}

// ---------------------------------------------------------------------------
// persistent 2-layer LSTM. 256 blocks x 512 threads (8 waves).
// Block b owns layer1 units [4b,4b+4), layer2 units [8b,8b+8).
// Iteration t (r10 structure + h2-gather moved to next iter's seg1):
//  seg1: waves0-3: phase A (h1[t] gsums, 4 rows each)
//        waves4-7: gather h2[t-3] (published iter t-1 seg3 -> in flight
//                  through h1-gather + S3 -> first-poll hit)        -> S1
//  seg2: wave0: gates1 + publish h1[t] || waves1-7: phase B          -> S2
//  seg3: wave0: gates2 + publish h2[t-2] + partial
//        waves4-7: gather h1[t] (in flight during phase B)           -> S3
// NO gather polls in the same segment as its publish.
// ---------------------------------------------------------------------------
__global__ __launch_bounds__(TPB, 1) void lstm_persist(
    const float* __restrict__ x,    const float* __restrict__ Wih1,
    const float* __restrict__ Whh1, const float* __restrict__ b1,
    const float* __restrict__ Wih2, const float* __restrict__ Whh2,
    const float* __restrict__ b2,   const float* __restrict__ Wout,
    uint32_t* __restrict__ lines,   float* __restrict__ partial_out)
{
  __shared__ u32x4 whh2_u4[32 * 256];   // 128 KiB f16 Whh2 (granules)
  __shared__ u32x4 h1g[2][128];         // h1 f16, double-buffered
  __shared__ u32x4 h2g[256];            // h2 f16
  __shared__ float gsum1[16], gx1v[16], gsum2[32], b2v[32];

  uint32_t* lines1 = lines;
  uint32_t* lines2 = lines + 4 * NCU * LINE_DW;

  const int b    = blockIdx.x;
  const int tid  = threadIdx.x;
  const int lane = tid & 63;
  const int wv   = tid >> 6;

  // ---- init: Whh2 slice -> LDS f16 granules ----
  for (int i = tid; i < 32 * 256; i += TPB) {
    int lr = i >> 8, u = i & 255;
    int g = lr >> 3, uu2 = lr & 7;
    const f32x4* s4 = (const f32x4*)(Whh2 + (int64_t)(g * HID2 + 8 * b + uu2) * HID2);
    f32x4 lo = s4[2 * u], hi = s4[2 * u + 1];
    u32x4 wv4;
    wv4[0] = pkh(lo[0], lo[1]); wv4[1] = pkh(lo[2], lo[3]);
    wv4[2] = pkh(hi[0], hi[1]); wv4[3] = pkh(hi[2], hi[3]);
    whh2_u4[i] = wv4;
  }

  // ---- waves 0-3: Whh1 rows lr1 = wv*4+rr in regs (f16 granules) ----
  u32x4 w1g[4][2];
  if (wv < 4) {
    #pragma unroll
    for (int rr = 0; rr < 4; ++rr) {
      int lr1 = wv * 4 + rr;
      int g = lr1 >> 2, uu = lr1 & 3;
      const f32x4* s4 = (const f32x4*)(Whh1 + (int64_t)(g * HID1 + 4 * b + uu) * IN_DIM);
      #pragma unroll
      for (int q = 0; q < 2; ++q) {
        int u = lane + 64 * q;
        f32x4 lo = s4[2 * u], hi = s4[2 * u + 1];
        u32x4 wv4;
        wv4[0] = pkh(lo[0], lo[1]); wv4[1] = pkh(lo[2], lo[3]);
        wv4[2] = pkh(hi[0], hi[1]); wv4[3] = pkh(hi[2], hi[3]);
        w1g[rr][q] = wv4;
      }
    }
  }

  // ---- waves 1..7: Wih2 rows lr = (wv-1)+7k, k<5, in regs ----
  u32x4 wi_reg[5][2];
  #pragma unroll
  for (int k = 0; k < 5; ++k) {
    int lr = (wv - 1) + 7 * k;
    if (wv >= 1 && lr < 32) {
      int g = lr >> 3, uu = lr & 7;
      const f32x4* s4 = (const f32x4*)(Wih2 + (int64_t)(g * HID2 + 8 * b + uu) * IN_DIM);
      #pragma unroll
      for (int q = 0; q < 2; ++q) {
        int u = lane + 64 * q;
        f32x4 lo = s4[2 * u], hi = s4[2 * u + 1];
        u32x4 wv4;
        wv4[0] = pkh(lo[0], lo[1]); wv4[1] = pkh(lo[2], lo[3]);
        wv4[2] = pkh(hi[0], hi[1]); wv4[3] = pkh(hi[2], hi[3]);
        wi_reg[k][q] = wv4;
      }
    }
  }

  // ---- gx1 = Wih1 @ x + b1 (constant over t; fp32, init-only) ----
  #pragma unroll
  for (int rr = 0; rr < 2; ++rr) {
    int lr1 = wv * 2 + rr;
    int g = lr1 >> 2, uu = lr1 & 3;
    int row = g * HID1 + 4 * b + uu;
    float s = 0.f;
    #pragma unroll
    for (int j = 0; j < 16; ++j)
      s += Wih1[(int64_t)row * IN_DIM + lane + 64 * j] * x[lane + 64 * j];
    s = wave_reduce(s);
    if (lane == 0) gx1v[lr1] = s + b1[row];
  }
  if (tid < 32) { int g = tid >> 3, uu = tid & 7; b2v[tid] = b2[g * HID2 + 8 * b + uu]; }
  {
    uint32_t* p1 = (uint32_t*)h1g;
    uint32_t* p2 = (uint32_t*)h2g;
    for (int i = tid; i < 2 * 128 * 4; i += TPB) p1[i] = 0u;
    for (int i = tid; i < 256 * 4;     i += TPB) p2[i] = 0u;
  }

  const float woutreg = Wout[8 * b + (lane & 7)];
  float c1reg = 0.f, c2reg = 0.f;
  __syncthreads();

  // ---- time loop ----
  for (int t = 0; t < T_STEPS + 2; ++t) {
    // ======== seg1: phase A (waves0-3) || gather h2[t-3] (waves4-7) ========
    if (wv < 4) {
      if (t < T_STEPS) {
        const u32x4* h1A = h1g[(t + 1) & 1];
        u32x4 ha0 = h1A[lane], ha1 = h1A[64 + lane];
        #pragma unroll
        for (int rr = 0; rr < 4; ++rr) {
          float s = dot16(w1g[rr][0], ha0, 0.f);
          s = dot16(w1g[rr][1], ha1, s);
          s = wave_reduce(s);
          if (lane == 0) gsum1[wv * 4 + rr] = s;
        }
      }
    } else {
      // gather h2[t-3], published at iter (t-1)'s seg3, tag t
      if (t >= 3 && t <= T_STEPS + 1) {
        const int j = tid - NCU;
        const uint32_t tg = (uint32_t)t;
        const uint32_t* l2 = lines2 + ((size_t)((t - 1) & 3) * NCU + j) * LINE_DW;
        for (;;) {
          u32x4 d0, d1, d2, d3;
          asm volatile("global_load_dwordx4 %0, %1, off sc0 sc1"
                       : "=&v"(d0) : "v"(l2));
          asm volatile("global_load_dwordx4 %0, %1, off offset:16 sc0 sc1"
                       : "=&v"(d1) : "v"(l2));
          asm volatile("global_load_dwordx4 %0, %1, off offset:32 sc0 sc1"
                       : "=&v"(d2) : "v"(l2));
          asm volatile("global_load_dwordx4 %0, %1, off offset:48 sc0 sc1"
                       : "=&v"(d3) : "v"(l2));
          asm volatile("s_waitcnt vmcnt(0)" ::: "memory");
          if (d0[1] == tg && d0[3] == tg && d1[1] == tg && d1[3] == tg &&
              d2[1] == tg && d2[3] == tg && d3[1] == tg && d3[3] == tg) {
            u32x4 hp;
            hp[0] = pkhu(d0[0], d0[2]); hp[1] = pkhu(d1[0], d1[2]);
            hp[2] = pkhu(d2[0], d2[2]); hp[3] = pkhu(d3[0], d3[2]);
            h2g[j] = hp;                       // becomes h2[t-3] for phase B
            break;
          }
          __builtin_amdgcn_s_sleep(1);
        }
      }
    }
    __syncthreads();   // S1: gsum1 + h2g ready

    // ======== seg2: wave0 gates1+publish h1 | waves1-7 phase B ========
    if (wv == 0) {
      if (t < T_STEPS) {
        const int u1 = lane & 3;
        float gi = sigm_(gsum1[u1]      + gx1v[u1]);
        float gf = sigm_(gsum1[4 + u1]  + gx1v[4 + u1]);
        float gg = tanh_(gsum1[8 + u1]  + gx1v[8 + u1]);
        float go = sigm_(gsum1[12 + u1] + gx1v[12 + u1]);
        c1reg = gf * c1reg + gi * gg;
        float h1v = go * tanh_(c1reg);         // unit (lane&3)
        if (lane < 4) {                        // LL pair store, fire-and-forget
          uint32_t* p = lines1 + ((size_t)(t & 3) * NCU + b) * LINE_DW + 2 * lane;
          u32x2 st; st[0] = __float_as_uint(h1v); st[1] = (uint32_t)(t + 1);
          asm volatile("global_store_dwordx2 %0, %1, off sc0 sc1"
                       :: "v"(p), "v"(st) : "memory");
        }
      }
    } else if (t >= 2) {
      const u32x4* h1B = h1g[t & 1];
      u32x4 x1a = h1B[lane], x1b = h1B[64 + lane];
      u32x4 x20 = h2g[lane],       x21 = h2g[64 + lane];
      u32x4 x22 = h2g[128 + lane], x23 = h2g[192 + lane];
      #pragma unroll
      for (int k = 0; k < 5; ++k) {
        const int lr = (wv - 1) + 7 * k;
        if (lr < 32) {
          float s = dot16(wi_reg[k][0], x1a, 0.f);
          s = dot16(wi_reg[k][1], x1b, s);
          s = dot16(whh2_u4[lr * 256 + lane],       x20, s);
          s = dot16(whh2_u4[lr * 256 + 64 + lane],  x21, s);
          s = dot16(whh2_u4[lr * 256 + 128 + lane], x22, s);
          s = dot16(whh2_u4[lr * 256 + 192 + lane], x23, s);
          s = wave_reduce(s);
          if (lane == 0) gsum2[lr] = s;
        }
      }
    }
    __syncthreads();   // S2: gsum2 ready; h1 lines in flight since seg2 start

    // ======== seg3: wave0 gates2+publish h2+partial | waves4-7 gather h1 ====
    if (wv == 0 && t >= 2) {
      const int u2 = lane & 7;
      float gi = sigm_(gsum2[u2]      + b2v[u2]);
      float gf = sigm_(gsum2[8 + u2]  + b2v[8 + u2]);
      float gg = tanh_(gsum2[16 + u2] + b2v[16 + u2]);
      float go = sigm_(gsum2[24 + u2] + b2v[24 + u2]);
      c2reg = gf * c2reg + gi * gg;
      float h2v = go * tanh_(c2reg);           // unit (lane&7)
      if (t <= T_STEPS && lane < 8) {          // LL pair store
        uint32_t* p = lines2 + ((size_t)(t & 3) * NCU + b) * LINE_DW + 2 * lane;
        u32x2 st; st[0] = __float_as_uint(h2v); st[1] = (uint32_t)(t + 1);
        asm volatile("global_store_dwordx2 %0, %1, off sc0 sc1"
                     :: "v"(p), "v"(st) : "memory");
      }
      float contrib = (lane < 8) ? h2v * woutreg : 0.f;
      float po = wave_reduce(contrib);
      if (lane == 0) partial_out[(int64_t)(t - 2) * NCU + b] = po;
    }
    if (wv >= 4 && t < T_STEPS) {
      // gather h1[t]: published at seg2 start, phase B flight time elapsed
      const int j = tid - NCU;
      const uint32_t tg = (uint32_t)(t + 1);
      const uint32_t* l1 = lines1 + ((size_t)(t & 3) * NCU + j) * LINE_DW;
      for (;;) {
        u32x4 a0, a1;
        asm volatile("global_load_dwordx4 %0, %1, off sc0 sc1"
                     : "=&v"(a0) : "v"(l1));
        asm volatile("global_load_dwordx4 %0, %1, off offset:16 sc0 sc1"
                     : "=&v"(a1) : "v"(l1));
        asm volatile("s_waitcnt vmcnt(0)" ::: "memory");
        if (a0[1] == tg && a0[3] == tg && a1[1] == tg && a1[3] == tg) {
          u32x2 hp; hp[0] = pkhu(a0[0], a0[2]); hp[1] = pkhu(a1[0], a1[2]);
          ((u32x2*)h1g[t & 1])[j] = hp;        // becomes h1[t]
          break;
        }
        __builtin_amdgcn_s_sleep(1);
      }
    }
    __syncthreads();   // S3
  }
}

// ---------------------------------------------------------------------------
// out[t] = sum_b partial_out[t][b] + bout
// ---------------------------------------------------------------------------
__global__ void out_reduce(const float* __restrict__ partial_out,
                           const float* __restrict__ bout,
                           float* __restrict__ out)
{
  int t = blockIdx.x;
  int lane = threadIdx.x;   // 64 threads
  float s = 0.f;
  #pragma unroll
  for (int q = 0; q < 4; ++q) s += partial_out[(int64_t)t * NCU + lane + 64 * q];
  s = wave_reduce(s);
  if (lane == 0) out[t] = s + bout[0];
}

extern "C" void kernel_launch(void* const* d_in, const int* in_sizes, int n_in,
                              void* d_out, int out_size, void* d_ws, size_t ws_size,
                              hipStream_t stream)
{
  const float* x    = (const float*)d_in[0];
  const float* Wih1 = (const float*)d_in[1];
  const float* Whh1 = (const float*)d_in[2];
  const float* b1   = (const float*)d_in[3];
  const float* Wih2 = (const float*)d_in[4];
  const float* Whh2 = (const float*)d_in[5];
  const float* b2   = (const float*)d_in[6];
  const float* Wout = (const float*)d_in[7];
  const float* bout = (const float*)d_in[8];
  float* out = (float*)d_out;

  char* ws = (char*)d_ws;
  size_t off = 0;
  auto take = [&](size_t bytes) -> char* {
    char* p = ws + off;
    off = (off + bytes + 255) & ~(size_t)255;
    return p;
  };
  uint32_t* lines    = (uint32_t*)take((size_t)2 * 4 * NCU * LINE_DW * 4); // 128 KB
  float* partial_out = (float*)take((size_t)T_STEPS * NCU * 4);            // 2 MB

  if (off > ws_size) return;

  hipLaunchKernelGGL(prep_kernel, dim3(32), dim3(256), 0, stream, lines);

  void* args[] = { &x, &Wih1, &Whh1, &b1, &Wih2, &Whh2, &b2, &Wout,
                   &lines, &partial_out };
  (void)hipLaunchCooperativeKernel((void*)lstm_persist, dim3(NCU), dim3(TPB),
                                   args, 0, stream);

  hipLaunchKernelGGL(out_reduce, dim3(T_STEPS), dim3(64), 0, stream,
                     partial_out, bout, out);
}

// Round 14
// 5165.087 us; speedup vs baseline: 3.1509x; 1.2886x over previous
//
#include <hip/hip_runtime.h>
#include <stdint.h>

#define NCU 256
#define TPB 512
#define IN_DIM 1024
#define HID1   1024
#define HID2   2048
#define T_STEPS 2048

// LL exchange (r10, proven): {payload,tag} 8-B pairs inside ONE 64-B sector.
// 8-B store = single transaction -> tag visible <=> payload visible.
// lines1: 4 pairs (h1). lines2: 8 pairs (h2). 64-B stride, 4 buffers deep.
#define LINE_DW 16

typedef float    f32x4 __attribute__((ext_vector_type(4)));
typedef uint32_t u32x4 __attribute__((ext_vector_type(4)));
typedef uint32_t u32x2 __attribute__((ext_vector_type(2)));
typedef __fp16   h16x2 __attribute__((ext_vector_type(2)));

__device__ __forceinline__ uint32_t pkh(float a, float b){
  h16x2 h = __builtin_amdgcn_cvt_pkrtz(a, b);
  uint32_t u; __builtin_memcpy(&u, &h, 4); return u;
}
__device__ __forceinline__ uint32_t pkhu(uint32_t a, uint32_t b){
  return pkh(__uint_as_float(a), __uint_as_float(b));
}

#if __has_builtin(__builtin_amdgcn_fdot2)
__device__ __forceinline__ float fdot2_(uint32_t w, uint32_t h, float c){
  h16x2 wf, hf; __builtin_memcpy(&wf, &w, 4); __builtin_memcpy(&hf, &h, 4);
  return __builtin_amdgcn_fdot2(wf, hf, c, false);
}
#else
__device__ __forceinline__ float fdot2_(uint32_t w, uint32_t h, float c){
  h16x2 wf, hf; __builtin_memcpy(&wf, &w, 4); __builtin_memcpy(&hf, &h, 4);
  c = fmaf((float)wf[0], (float)hf[0], c);
  return fmaf((float)wf[1], (float)hf[1], c);
}
#endif

__device__ __forceinline__ float dot16(u32x4 w, u32x4 h, float c){
  c = fdot2_(w[0], h[0], c); c = fdot2_(w[1], h[1], c);
  c = fdot2_(w[2], h[2], c); c = fdot2_(w[3], h[3], c);
  return c;
}

__device__ __forceinline__ float wave_reduce(float v){
  v += __shfl_xor(v, 32); v += __shfl_xor(v, 16); v += __shfl_xor(v, 8);
  v += __shfl_xor(v, 4);  v += __shfl_xor(v, 2);  v += __shfl_xor(v, 1);
  return v;
}

__device__ __forceinline__ float sigm_(float x){
  return __builtin_amdgcn_rcpf(1.f + __expf(-x));
}
__device__ __forceinline__ float tanh_(float x){
  float e = __expf(2.f * x);
  return (e - 1.f) * __builtin_amdgcn_rcpf(e + 1.f);
}

__global__ void prep_kernel(uint32_t* __restrict__ lines)
{
  int idx = blockIdx.x * blockDim.x + threadIdx.x;
  const int total = 2 * 4 * NCU * LINE_DW;
  for (int i = idx; i < total; i += gridDim.x * blockDim.x)
    __hip_atomic_store(lines + i, 0u, __ATOMIC_RELAXED, __HIP_MEMORY_SCOPE_AGENT);
}

// ---------------------------------------------------------------------------
// persistent 2-layer LSTM. 256 blocks x 512 threads (8 waves).
// Block b owns layer1 units [4b,4b+4), layer2 units [8b,8b+8).
// UNIT-OWNER: wave wv owns L1 unit wv (wv<4: rows g*4+wv) and L2 unit wv
// (rows g*8+wv). After its 4 wave-reduces (broadcasting), the wave computes
// gates + c-state in-wave and publishes immediately. No gsum LDS handoff.
// Iteration t (2 barriers):
//  seg1: waves0-3: phaseA(t) -> gates1 -> publish h1[t] (end of phaseA)
//        waves4-7: gather h2[t-3] (published prior seg2, flight=S2)   -> S1
//  seg2: all: phaseB(t) -> gates2 -> publish h2[t-2] + partial (pre-barrier)
//        then waves4-7: gather h1[t] (flight = S1 + phaseB)           -> S2
// h1 triple-buffered: phaseA(t) reads h1buf[(t+2)%3] (=h1[t-1]); phaseB(t)
// reads h1buf[(t+1)%3] (=h1[t-2]); gather writes h1buf[t%3] (=h1[t]).
// h2 single LDS buffer: gathered seg1, read seg2, barrier between.
// ---------------------------------------------------------------------------
__global__ __launch_bounds__(TPB, 1) void lstm_persist(
    const float* __restrict__ x,    const float* __restrict__ Wih1,
    const float* __restrict__ Whh1, const float* __restrict__ b1,
    const float* __restrict__ Wih2, const float* __restrict__ Whh2,
    const float* __restrict__ b2,   const float* __restrict__ Wout,
    uint32_t* __restrict__ lines,   float* __restrict__ partial_out)
{
  __shared__ u32x4 whh2_u4[32 * 256];   // 128 KiB f16 Whh2 (granules)
  __shared__ u32x4 h1buf[3][128];       // h1 f16, triple-buffered (3 x 2 KiB)
  __shared__ u32x4 h2g[256];            // h2 f16 (4 KiB)
  __shared__ float gx1v[16];

  uint32_t* lines1 = lines;
  uint32_t* lines2 = lines + 4 * NCU * LINE_DW;

  const int b    = blockIdx.x;
  const int tid  = threadIdx.x;
  const int lane = tid & 63;
  const int wv   = tid >> 6;

  // ---- init: Whh2 slice -> LDS f16 granules ----
  for (int i = tid; i < 32 * 256; i += TPB) {
    int lr = i >> 8, u = i & 255;
    int g = lr >> 3, uu2 = lr & 7;
    const f32x4* s4 = (const f32x4*)(Whh2 + (int64_t)(g * HID2 + 8 * b + uu2) * HID2);
    f32x4 lo = s4[2 * u], hi = s4[2 * u + 1];
    u32x4 wv4;
    wv4[0] = pkh(lo[0], lo[1]); wv4[1] = pkh(lo[2], lo[3]);
    wv4[2] = pkh(hi[0], hi[1]); wv4[3] = pkh(hi[2], hi[3]);
    whh2_u4[i] = wv4;
  }

  // ---- gx1 = Wih1 @ x + b1 (constant over t; 2 rows/wave) ----
  #pragma unroll
  for (int rr = 0; rr < 2; ++rr) {
    int lr1 = wv * 2 + rr;
    int g = lr1 >> 2, uu = lr1 & 3;
    int row = g * HID1 + 4 * b + uu;
    float s = 0.f;
    #pragma unroll
    for (int j = 0; j < 16; ++j)
      s += Wih1[(int64_t)row * IN_DIM + lane + 64 * j] * x[lane + 64 * j];
    s = wave_reduce(s);
    if (lane == 0) gx1v[lr1] = s + b1[row];
  }
  {
    u32x4 z; z[0] = z[1] = z[2] = z[3] = 0u;
    for (int i = tid; i < 3 * 128; i += TPB) ((u32x4*)h1buf)[i] = z;
    for (int i = tid; i < 256;     i += TPB) h2g[i] = z;
  }
  __syncthreads();   // gx1v ready

  // ---- per-wave weights in registers ----
  // waves 0-3: Whh1 rows g*HID1 + 4b + wv (L1 unit wv), 2 granules/row.
  u32x4 w1reg[4][2];
  float bias1[4];
  if (wv < 4) {
    #pragma unroll
    for (int g = 0; g < 4; ++g) {
      const f32x4* s4 = (const f32x4*)(Whh1 + (int64_t)(g * HID1 + 4 * b + wv) * IN_DIM);
      #pragma unroll
      for (int q = 0; q < 2; ++q) {
        int u = lane + 64 * q;
        f32x4 lo = s4[2 * u], hi = s4[2 * u + 1];
        u32x4 w4;
        w4[0] = pkh(lo[0], lo[1]); w4[1] = pkh(lo[2], lo[3]);
        w4[2] = pkh(hi[0], hi[1]); w4[3] = pkh(hi[2], hi[3]);
        w1reg[g][q] = w4;
      }
      bias1[g] = gx1v[g * 4 + wv];
    }
  }
  // all waves: Wih2 rows g*HID2 + 8b + wv (L2 unit wv), 2 granules/row.
  u32x4 wi2reg[4][2];
  float bias2[4];
  #pragma unroll
  for (int g = 0; g < 4; ++g) {
    const f32x4* s4 = (const f32x4*)(Wih2 + (int64_t)(g * HID2 + 8 * b + wv) * IN_DIM);
    #pragma unroll
    for (int q = 0; q < 2; ++q) {
      int u = lane + 64 * q;
      f32x4 lo = s4[2 * u], hi = s4[2 * u + 1];
      u32x4 w4;
      w4[0] = pkh(lo[0], lo[1]); w4[1] = pkh(lo[2], lo[3]);
      w4[2] = pkh(hi[0], hi[1]); w4[3] = pkh(hi[2], hi[3]);
      wi2reg[g][q] = w4;
    }
    bias2[g] = b2[g * HID2 + 8 * b + wv];
  }
  const float woutr = Wout[8 * b + wv];

  float creg1 = 0.f, creg2 = 0.f;
  __syncthreads();

  // ---- time loop: TWO barriers per iteration ----
  for (int t = 0; t < T_STEPS + 2; ++t) {
    // ======== seg1: phaseA+gates1+publish (w0-3) || gather h2[t-3] (w4-7) ===
    if (wv < 4) {
      if (t < T_STEPS) {
        const u32x4* h1A = h1buf[(t + 2) % 3];      // h1[t-1]
        u32x4 ha0 = h1A[lane], ha1 = h1A[64 + lane];
        float a0 = dot16(w1reg[0][1], ha1, dot16(w1reg[0][0], ha0, 0.f));
        float a1 = dot16(w1reg[1][1], ha1, dot16(w1reg[1][0], ha0, 0.f));
        float a2 = dot16(w1reg[2][1], ha1, dot16(w1reg[2][0], ha0, 0.f));
        float a3 = dot16(w1reg[3][1], ha1, dot16(w1reg[3][0], ha0, 0.f));
        a0 = wave_reduce(a0); a1 = wave_reduce(a1);
        a2 = wave_reduce(a2); a3 = wave_reduce(a3);
        float gi = sigm_(a0 + bias1[0]);
        float gf = sigm_(a1 + bias1[1]);
        float gg = tanh_(a2 + bias1[2]);
        float go = sigm_(a3 + bias1[3]);
        creg1 = gf * creg1 + gi * gg;
        float h1v = go * tanh_(creg1);
        if (lane == 0) {                // publish pair wv (LL, fire-and-forget)
          uint32_t* p = lines1 + ((size_t)(t & 3) * NCU + b) * LINE_DW + 2 * wv;
          u32x2 st; st[0] = __float_as_uint(h1v); st[1] = (uint32_t)(t + 1);
          asm volatile("global_store_dwordx2 %0, %1, off sc0 sc1"
                       :: "v"(p), "v"(st) : "memory");
        }
      }
    } else {
      // gather h2[t-3]: published iter t-1 seg2, tag t, buffer (t-1)&3
      if (t >= 3 && t <= T_STEPS + 1) {
        const int j = tid - NCU;
        const uint32_t tg = (uint32_t)t;
        const uint32_t* l2 = lines2 + ((size_t)((t - 1) & 3) * NCU + j) * LINE_DW;
        for (;;) {
          u32x4 d0, d1, d2, d3;
          asm volatile("global_load_dwordx4 %0, %1, off sc0 sc1"
                       : "=&v"(d0) : "v"(l2));
          asm volatile("global_load_dwordx4 %0, %1, off offset:16 sc0 sc1"
                       : "=&v"(d1) : "v"(l2));
          asm volatile("global_load_dwordx4 %0, %1, off offset:32 sc0 sc1"
                       : "=&v"(d2) : "v"(l2));
          asm volatile("global_load_dwordx4 %0, %1, off offset:48 sc0 sc1"
                       : "=&v"(d3) : "v"(l2));
          asm volatile("s_waitcnt vmcnt(0)" ::: "memory");
          if (d0[1] == tg && d0[3] == tg && d1[1] == tg && d1[3] == tg &&
              d2[1] == tg && d2[3] == tg && d3[1] == tg && d3[3] == tg) {
            u32x4 hp;
            hp[0] = pkhu(d0[0], d0[2]); hp[1] = pkhu(d1[0], d1[2]);
            hp[2] = pkhu(d2[0], d2[2]); hp[3] = pkhu(d3[0], d3[2]);
            h2g[j] = hp;                 // h2[t-3] for phase B this iter
            break;
          }
          __builtin_amdgcn_s_sleep(1);
        }
      }
    }
    __syncthreads();   // S1

    // ======== seg2: phaseB+gates2+publish (all) ; then gather h1 (w4-7) ====
    if (t >= 2) {
      const u32x4* h1B = h1buf[(t + 1) % 3];        // h1[t-2]
      u32x4 x1a = h1B[lane], x1b = h1B[64 + lane];
      u32x4 x20 = h2g[lane],       x21 = h2g[64 + lane];
      u32x4 x22 = h2g[128 + lane], x23 = h2g[192 + lane];
      float acc[4];
      #pragma unroll
      for (int g = 0; g < 4; ++g) {
        const u32x4* wrow = &whh2_u4[(g * 8 + wv) * 256];
        float s = dot16(wi2reg[g][0], x1a, 0.f);
        s = dot16(wi2reg[g][1], x1b, s);
        s = dot16(wrow[lane],       x20, s);
        s = dot16(wrow[64 + lane],  x21, s);
        s = dot16(wrow[128 + lane], x22, s);
        s = dot16(wrow[192 + lane], x23, s);
        acc[g] = wave_reduce(s);
      }
      float gi = sigm_(acc[0] + bias2[0]);
      float gf = sigm_(acc[1] + bias2[1]);
      float gg = tanh_(acc[2] + bias2[2]);
      float go = sigm_(acc[3] + bias2[3]);
      creg2 = gf * creg2 + gi * gg;
      float h2v = go * tanh_(creg2);
      if (lane == 0) {
        if (t <= T_STEPS) {             // publish pair wv (LL)
          uint32_t* p = lines2 + ((size_t)(t & 3) * NCU + b) * LINE_DW + 2 * wv;
          u32x2 st; st[0] = __float_as_uint(h2v); st[1] = (uint32_t)(t + 1);
          asm volatile("global_store_dwordx2 %0, %1, off sc0 sc1"
                       :: "v"(p), "v"(st) : "memory");
        }
        partial_out[((int64_t)(t - 2) * NCU + b) * 8 + wv] = h2v * woutr;
      }
    }
    if (wv >= 4 && t < T_STEPS) {
      // gather h1[t]: published end of seg1, flight = S1 + phaseB
      const int j = tid - NCU;
      const uint32_t tg = (uint32_t)(t + 1);
      const uint32_t* l1 = lines1 + ((size_t)(t & 3) * NCU + j) * LINE_DW;
      for (;;) {
        u32x4 a0, a1;
        asm volatile("global_load_dwordx4 %0, %1, off sc0 sc1"
                     : "=&v"(a0) : "v"(l1));
        asm volatile("global_load_dwordx4 %0, %1, off offset:16 sc0 sc1"
                     : "=&v"(a1) : "v"(l1));
        asm volatile("s_waitcnt vmcnt(0)" ::: "memory");
        if (a0[1] == tg && a0[3] == tg && a1[1] == tg && a1[3] == tg) {
          u32x2 hp; hp[0] = pkhu(a0[0], a0[2]); hp[1] = pkhu(a1[0], a1[2]);
          ((u32x2*)h1buf[t % 3])[j] = hp;        // h1[t]
          break;
        }
        __builtin_amdgcn_s_sleep(1);
      }
    }
    __syncthreads();   // S2
  }
}

// ---------------------------------------------------------------------------
// out[t] = sum over 2048 per-unit partials + bout
// ---------------------------------------------------------------------------
__global__ void out_reduce(const float* __restrict__ partial_out,
                           const float* __restrict__ bout,
                           float* __restrict__ out)
{
  int t = blockIdx.x;
  int lane = threadIdx.x;   // 64 threads
  float s = 0.f;
  #pragma unroll
  for (int q = 0; q < 32; ++q)
    s += partial_out[(int64_t)t * (NCU * 8) + lane + 64 * q];
  s = wave_reduce(s);
  if (lane == 0) out[t] = s + bout[0];
}

extern "C" void kernel_launch(void* const* d_in, const int* in_sizes, int n_in,
                              void* d_out, int out_size, void* d_ws, size_t ws_size,
                              hipStream_t stream)
{
  const float* x    = (const float*)d_in[0];
  const float* Wih1 = (const float*)d_in[1];
  const float* Whh1 = (const float*)d_in[2];
  const float* b1   = (const float*)d_in[3];
  const float* Wih2 = (const float*)d_in[4];
  const float* Whh2 = (const float*)d_in[5];
  const float* b2   = (const float*)d_in[6];
  const float* Wout = (const float*)d_in[7];
  const float* bout = (const float*)d_in[8];
  float* out = (float*)d_out;

  char* ws = (char*)d_ws;
  size_t off = 0;
  auto take = [&](size_t bytes) -> char* {
    char* p = ws + off;
    off = (off + bytes + 255) & ~(size_t)255;
    return p;
  };
  uint32_t* lines    = (uint32_t*)take((size_t)2 * 4 * NCU * LINE_DW * 4);  // 128 KB
  float* partial_out = (float*)take((size_t)T_STEPS * NCU * 8 * 4);         // 16.8 MB

  if (off > ws_size) return;

  hipLaunchKernelGGL(prep_kernel, dim3(32), dim3(256), 0, stream, lines);

  void* args[] = { &x, &Wih1, &Whh1, &b1, &Wih2, &Whh2, &b2, &Wout,
                   &lines, &partial_out };
  (void)hipLaunchCooperativeKernel((void*)lstm_persist, dim3(NCU), dim3(TPB),
                                   args, 0, stream);

  hipLaunchKernelGGL(out_reduce, dim3(T_STEPS), dim3(64), 0, stream,
                     partial_out, bout, out);
}

// Round 15
// 4788.441 us; speedup vs baseline: 3.3987x; 1.0787x over previous
//
#include <hip/hip_runtime.h>
#include <stdint.h>

#define NCU 256
#define TPB 512
#define IN_DIM 1024
#define HID1   1024
#define HID2   2048
#define T_STEPS 2048

// LL exchange (r10, proven): {payload,tag} 8-B pairs inside ONE 64-B sector.
// 8-B store = single transaction -> tag visible <=> payload visible.
// lines1: 4 pairs (h1). lines2: 8 pairs (h2). 64-B stride, 4 buffers deep.
#define LINE_DW 16

typedef float    f32x4 __attribute__((ext_vector_type(4)));
typedef uint32_t u32x4 __attribute__((ext_vector_type(4)));
typedef uint32_t u32x2 __attribute__((ext_vector_type(2)));
typedef __fp16   h16x2 __attribute__((ext_vector_type(2)));

__device__ __forceinline__ uint32_t pkh(float a, float b){
  h16x2 h = __builtin_amdgcn_cvt_pkrtz(a, b);
  uint32_t u; __builtin_memcpy(&u, &h, 4); return u;
}
__device__ __forceinline__ uint32_t pkhu(uint32_t a, uint32_t b){
  return pkh(__uint_as_float(a), __uint_as_float(b));
}

#if __has_builtin(__builtin_amdgcn_fdot2)
__device__ __forceinline__ float fdot2_(uint32_t w, uint32_t h, float c){
  h16x2 wf, hf; __builtin_memcpy(&wf, &w, 4); __builtin_memcpy(&hf, &h, 4);
  return __builtin_amdgcn_fdot2(wf, hf, c, false);
}
#else
__device__ __forceinline__ float fdot2_(uint32_t w, uint32_t h, float c){
  h16x2 wf, hf; __builtin_memcpy(&wf, &w, 4); __builtin_memcpy(&hf, &h, 4);
  c = fmaf((float)wf[0], (float)hf[0], c);
  return fmaf((float)wf[1], (float)hf[1], c);
}
#endif

__device__ __forceinline__ float dot16(u32x4 w, u32x4 h, float c){
  c = fdot2_(w[0], h[0], c); c = fdot2_(w[1], h[1], c);
  c = fdot2_(w[2], h[2], c); c = fdot2_(w[3], h[3], c);
  return c;
}

__device__ __forceinline__ float wave_reduce(float v){
  v += __shfl_xor(v, 32); v += __shfl_xor(v, 16); v += __shfl_xor(v, 8);
  v += __shfl_xor(v, 4);  v += __shfl_xor(v, 2);  v += __shfl_xor(v, 1);
  return v;
}

__device__ __forceinline__ float sigm_(float x){
  return __builtin_amdgcn_rcpf(1.f + __expf(-x));
}
__device__ __forceinline__ float tanh_(float x){
  float e = __expf(2.f * x);
  return (e - 1.f) * __builtin_amdgcn_rcpf(e + 1.f);
}

__global__ void prep_kernel(uint32_t* __restrict__ lines)
{
  int idx = blockIdx.x * blockDim.x + threadIdx.x;
  const int total = 2 * 4 * NCU * LINE_DW;
  for (int i = idx; i < total; i += gridDim.x * blockDim.x)
    __hip_atomic_store(lines + i, 0u, __ATOMIC_RELAXED, __HIP_MEMORY_SCOPE_AGENT);
}

// ---------------------------------------------------------------------------
// persistent 2-layer LSTM. 256 blocks x 512 threads (8 waves).
// Block b owns layer1 units [4b,4b+4), layer2 units [8b,8b+8).
// UNIT-OWNER (r14) + ALL weights in registers (Whh2 LDS -> 64 VGPR/wave):
// phase B LDS traffic drops 22 -> 6 ds_read_b128 per wave per step.
// Iteration t (2 barriers):
//  seg1: waves0-3: phaseA(t) -> gates1 -> publish h1[t]
//        waves4-7: gather h2[t-3] (published prior seg2, flight=S2)   -> S1
//  seg2: all: phaseB(t) -> gates2 -> publish h2[t-2] + partial
//        then waves4-7: gather h1[t] (flight = S1 + phaseB)           -> S2
// h1 triple-buffered; h2 single buffer (gathered seg1, read seg2).
// ---------------------------------------------------------------------------
__global__ __launch_bounds__(TPB, 1) void lstm_persist(
    const float* __restrict__ x,    const float* __restrict__ Wih1,
    const float* __restrict__ Whh1, const float* __restrict__ b1,
    const float* __restrict__ Wih2, const float* __restrict__ Whh2,
    const float* __restrict__ b2,   const float* __restrict__ Wout,
    uint32_t* __restrict__ lines,   float* __restrict__ partial_out)
{
  __shared__ u32x4 h1buf[3][128];       // h1 f16, triple-buffered (3 x 2 KiB)
  __shared__ u32x4 h2g[256];            // h2 f16 (4 KiB)
  __shared__ float gx1v[16];

  uint32_t* lines1 = lines;
  uint32_t* lines2 = lines + 4 * NCU * LINE_DW;

  const int b    = blockIdx.x;
  const int tid  = threadIdx.x;
  const int lane = tid & 63;
  const int wv   = tid >> 6;

  // ---- gx1 = Wih1 @ x + b1 (constant over t; 2 rows/wave) ----
  #pragma unroll
  for (int rr = 0; rr < 2; ++rr) {
    int lr1 = wv * 2 + rr;
    int g = lr1 >> 2, uu = lr1 & 3;
    int row = g * HID1 + 4 * b + uu;
    float s = 0.f;
    #pragma unroll
    for (int j = 0; j < 16; ++j)
      s += Wih1[(int64_t)row * IN_DIM + lane + 64 * j] * x[lane + 64 * j];
    s = wave_reduce(s);
    if (lane == 0) gx1v[lr1] = s + b1[row];
  }
  {
    u32x4 z; z[0] = z[1] = z[2] = z[3] = 0u;
    for (int i = tid; i < 3 * 128; i += TPB) ((u32x4*)h1buf)[i] = z;
    for (int i = tid; i < 256;     i += TPB) h2g[i] = z;
  }
  __syncthreads();   // gx1v ready

  // ---- per-wave weights in registers ----
  // waves 0-3: Whh1 rows g*HID1 + 4b + wv (L1 unit wv), 2 granules/row.
  u32x4 w1reg[4][2];
  float bias1[4];
  if (wv < 4) {
    #pragma unroll
    for (int g = 0; g < 4; ++g) {
      const f32x4* s4 = (const f32x4*)(Whh1 + (int64_t)(g * HID1 + 4 * b + wv) * IN_DIM);
      #pragma unroll
      for (int q = 0; q < 2; ++q) {
        int u = lane + 64 * q;
        f32x4 lo = s4[2 * u], hi = s4[2 * u + 1];
        u32x4 w4;
        w4[0] = pkh(lo[0], lo[1]); w4[1] = pkh(lo[2], lo[3]);
        w4[2] = pkh(hi[0], hi[1]); w4[3] = pkh(hi[2], hi[3]);
        w1reg[g][q] = w4;
      }
      bias1[g] = gx1v[g * 4 + wv];
    }
  }
  // all waves: Wih2 rows g*HID2 + 8b + wv (L2 unit wv), 2 granules/row.
  u32x4 wi2reg[4][2];
  float bias2[4];
  #pragma unroll
  for (int g = 0; g < 4; ++g) {
    const f32x4* s4 = (const f32x4*)(Wih2 + (int64_t)(g * HID2 + 8 * b + wv) * IN_DIM);
    #pragma unroll
    for (int q = 0; q < 2; ++q) {
      int u = lane + 64 * q;
      f32x4 lo = s4[2 * u], hi = s4[2 * u + 1];
      u32x4 w4;
      w4[0] = pkh(lo[0], lo[1]); w4[1] = pkh(lo[2], lo[3]);
      w4[2] = pkh(hi[0], hi[1]); w4[3] = pkh(hi[2], hi[3]);
      wi2reg[g][q] = w4;
    }
    bias2[g] = b2[g * HID2 + 8 * b + wv];
  }
  // all waves: Whh2 rows g*HID2 + 8b + wv (L2 unit wv), 4 granules/row
  // (64 VGPRs - replaces the 128 KiB LDS staging of r14).
  u32x4 w2reg[4][4];
  #pragma unroll
  for (int g = 0; g < 4; ++g) {
    const f32x4* s4 = (const f32x4*)(Whh2 + (int64_t)(g * HID2 + 8 * b + wv) * HID2);
    #pragma unroll
    for (int q = 0; q < 4; ++q) {
      int u = lane + 64 * q;
      f32x4 lo = s4[2 * u], hi = s4[2 * u + 1];
      u32x4 w4;
      w4[0] = pkh(lo[0], lo[1]); w4[1] = pkh(lo[2], lo[3]);
      w4[2] = pkh(hi[0], hi[1]); w4[3] = pkh(hi[2], hi[3]);
      w2reg[g][q] = w4;
    }
  }
  const float woutr = Wout[8 * b + wv];

  float creg1 = 0.f, creg2 = 0.f;
  __syncthreads();

  // ---- time loop: TWO barriers per iteration ----
  for (int t = 0; t < T_STEPS + 2; ++t) {
    // ======== seg1: phaseA+gates1+publish (w0-3) || gather h2[t-3] (w4-7) ===
    if (wv < 4) {
      if (t < T_STEPS) {
        const u32x4* h1A = h1buf[(t + 2) % 3];      // h1[t-1]
        u32x4 ha0 = h1A[lane], ha1 = h1A[64 + lane];
        float a0 = dot16(w1reg[0][1], ha1, dot16(w1reg[0][0], ha0, 0.f));
        float a1 = dot16(w1reg[1][1], ha1, dot16(w1reg[1][0], ha0, 0.f));
        float a2 = dot16(w1reg[2][1], ha1, dot16(w1reg[2][0], ha0, 0.f));
        float a3 = dot16(w1reg[3][1], ha1, dot16(w1reg[3][0], ha0, 0.f));
        a0 = wave_reduce(a0); a1 = wave_reduce(a1);
        a2 = wave_reduce(a2); a3 = wave_reduce(a3);
        float gi = sigm_(a0 + bias1[0]);
        float gf = sigm_(a1 + bias1[1]);
        float gg = tanh_(a2 + bias1[2]);
        float go = sigm_(a3 + bias1[3]);
        creg1 = gf * creg1 + gi * gg;
        float h1v = go * tanh_(creg1);
        if (lane == 0) {                // publish pair wv (LL, fire-and-forget)
          uint32_t* p = lines1 + ((size_t)(t & 3) * NCU + b) * LINE_DW + 2 * wv;
          u32x2 st; st[0] = __float_as_uint(h1v); st[1] = (uint32_t)(t + 1);
          asm volatile("global_store_dwordx2 %0, %1, off sc0 sc1"
                       :: "v"(p), "v"(st) : "memory");
        }
      }
    } else {
      // gather h2[t-3]: published iter t-1 seg2, tag t, buffer (t-1)&3
      if (t >= 3 && t <= T_STEPS + 1) {
        const int j = tid - NCU;
        const uint32_t tg = (uint32_t)t;
        const uint32_t* l2 = lines2 + ((size_t)((t - 1) & 3) * NCU + j) * LINE_DW;
        for (;;) {
          u32x4 d0, d1, d2, d3;
          asm volatile("global_load_dwordx4 %0, %1, off sc0 sc1"
                       : "=&v"(d0) : "v"(l2));
          asm volatile("global_load_dwordx4 %0, %1, off offset:16 sc0 sc1"
                       : "=&v"(d1) : "v"(l2));
          asm volatile("global_load_dwordx4 %0, %1, off offset:32 sc0 sc1"
                       : "=&v"(d2) : "v"(l2));
          asm volatile("global_load_dwordx4 %0, %1, off offset:48 sc0 sc1"
                       : "=&v"(d3) : "v"(l2));
          asm volatile("s_waitcnt vmcnt(0)" ::: "memory");
          if (d0[1] == tg && d0[3] == tg && d1[1] == tg && d1[3] == tg &&
              d2[1] == tg && d2[3] == tg && d3[1] == tg && d3[3] == tg) {
            u32x4 hp;
            hp[0] = pkhu(d0[0], d0[2]); hp[1] = pkhu(d1[0], d1[2]);
            hp[2] = pkhu(d2[0], d2[2]); hp[3] = pkhu(d3[0], d3[2]);
            h2g[j] = hp;                 // h2[t-3] for phase B this iter
            break;
          }
          __builtin_amdgcn_s_sleep(1);
        }
      }
    }
    __syncthreads();   // S1

    // ======== seg2: phaseB+gates2+publish (all) ; then gather h1 (w4-7) ====
    if (t >= 2) {
      const u32x4* h1B = h1buf[(t + 1) % 3];        // h1[t-2]
      u32x4 x1a = h1B[lane], x1b = h1B[64 + lane];
      u32x4 x20 = h2g[lane],       x21 = h2g[64 + lane];
      u32x4 x22 = h2g[128 + lane], x23 = h2g[192 + lane];
      float acc[4];
      #pragma unroll
      for (int g = 0; g < 4; ++g) {
        float s = dot16(wi2reg[g][0], x1a, 0.f);
        s = dot16(wi2reg[g][1], x1b, s);
        s = dot16(w2reg[g][0], x20, s);
        s = dot16(w2reg[g][1], x21, s);
        s = dot16(w2reg[g][2], x22, s);
        s = dot16(w2reg[g][3], x23, s);
        acc[g] = wave_reduce(s);
      }
      float gi = sigm_(acc[0] + bias2[0]);
      float gf = sigm_(acc[1] + bias2[1]);
      float gg = tanh_(acc[2] + bias2[2]);
      float go = sigm_(acc[3] + bias2[3]);
      creg2 = gf * creg2 + gi * gg;
      float h2v = go * tanh_(creg2);
      if (lane == 0) {
        if (t <= T_STEPS) {             // publish pair wv (LL)
          uint32_t* p = lines2 + ((size_t)(t & 3) * NCU + b) * LINE_DW + 2 * wv;
          u32x2 st; st[0] = __float_as_uint(h2v); st[1] = (uint32_t)(t + 1);
          asm volatile("global_store_dwordx2 %0, %1, off sc0 sc1"
                       :: "v"(p), "v"(st) : "memory");
        }
        partial_out[((int64_t)(t - 2) * NCU + b) * 8 + wv] = h2v * woutr;
      }
    }
    if (wv >= 4 && t < T_STEPS) {
      // gather h1[t]: published end of seg1, flight = S1 + phaseB
      const int j = tid - NCU;
      const uint32_t tg = (uint32_t)(t + 1);
      const uint32_t* l1 = lines1 + ((size_t)(t & 3) * NCU + j) * LINE_DW;
      for (;;) {
        u32x4 a0, a1;
        asm volatile("global_load_dwordx4 %0, %1, off sc0 sc1"
                     : "=&v"(a0) : "v"(l1));
        asm volatile("global_load_dwordx4 %0, %1, off offset:16 sc0 sc1"
                     : "=&v"(a1) : "v"(l1));
        asm volatile("s_waitcnt vmcnt(0)" ::: "memory");
        if (a0[1] == tg && a0[3] == tg && a1[1] == tg && a1[3] == tg) {
          u32x2 hp; hp[0] = pkhu(a0[0], a0[2]); hp[1] = pkhu(a1[0], a1[2]);
          ((u32x2*)h1buf[t % 3])[j] = hp;        // h1[t]
          break;
        }
        __builtin_amdgcn_s_sleep(1);
      }
    }
    __syncthreads();   // S2
  }
}

// ---------------------------------------------------------------------------
// out[t] = sum over 2048 per-unit partials + bout
// ---------------------------------------------------------------------------
__global__ void out_reduce(const float* __restrict__ partial_out,
                           const float* __restrict__ bout,
                           float* __restrict__ out)
{
  int t = blockIdx.x;
  int lane = threadIdx.x;   // 64 threads
  float s = 0.f;
  #pragma unroll
  for (int q = 0; q < 32; ++q)
    s += partial_out[(int64_t)t * (NCU * 8) + lane + 64 * q];
  s = wave_reduce(s);
  if (lane == 0) out[t] = s + bout[0];
}

extern "C" void kernel_launch(void* const* d_in, const int* in_sizes, int n_in,
                              void* d_out, int out_size, void* d_ws, size_t ws_size,
                              hipStream_t stream)
{
  const float* x    = (const float*)d_in[0];
  const float* Wih1 = (const float*)d_in[1];
  const float* Whh1 = (const float*)d_in[2];
  const float* b1   = (const float*)d_in[3];
  const float* Wih2 = (const float*)d_in[4];
  const float* Whh2 = (const float*)d_in[5];
  const float* b2   = (const float*)d_in[6];
  const float* Wout = (const float*)d_in[7];
  const float* bout = (const float*)d_in[8];
  float* out = (float*)d_out;

  char* ws = (char*)d_ws;
  size_t off = 0;
  auto take = [&](size_t bytes) -> char* {
    char* p = ws + off;
    off = (off + bytes + 255) & ~(size_t)255;
    return p;
  };
  uint32_t* lines    = (uint32_t*)take((size_t)2 * 4 * NCU * LINE_DW * 4);  // 128 KB
  float* partial_out = (float*)take((size_t)T_STEPS * NCU * 8 * 4);         // 16.8 MB

  if (off > ws_size) return;

  hipLaunchKernelGGL(prep_kernel, dim3(32), dim3(256), 0, stream, lines);

  void* args[] = { &x, &Wih1, &Whh1, &b1, &Wih2, &Whh2, &b2, &Wout,
                   &lines, &partial_out };
  (void)hipLaunchCooperativeKernel((void*)lstm_persist, dim3(NCU), dim3(TPB),
                                   args, 0, stream);

  hipLaunchKernelGGL(out_reduce, dim3(T_STEPS), dim3(64), 0, stream,
                     partial_out, bout, out);
}